// Round 18
// baseline (142610.767 us; speedup 1.0000x reference)
//
#include <hip/hip_runtime.h>
#include <math.h>

// LSTM T=32768, B=1, I=128, H=512. R18: R12 protocol with HALF the agents.
// 16 WGs x 512 threads; each WG owns 32 h elements (128 gate rows), each
// thread computes 2 rows (128 W_hh weights in VGPRs; 256-VGPR budget).
// Sync protocol byte-identical to R12 (best, 65.6k): tag-in-band 8B packets,
// wave0 polls-then-computes (4 loads/lane, per-lane early-out), parity-
// double-buffered LDS, LDS-staged coalesced publish (16 packets = 128B per
// WG), atomic-free out[]. Tests whether the max-over-N producer/consumer
// skew term scales with agent count N (32 -> 16).

#define T_SEQ 32768
#define HID   512
#define INP   128
#define NWG   16
#define NTH   512   // 8 waves; wave0 polls then computes
#define KW    64    // W_hh weights per row-chunk
#define KX    16    // W_ih weights per row-chunk
#define NPK   256   // packets per parity (2 h each)

typedef unsigned long long u64;
typedef unsigned int u32;

__device__ __forceinline__ float fast_sigmoid(float x) {
    return 1.0f / (1.0f + __expf(-x));
}
__device__ __forceinline__ float fast_tanh(float x) {
    float a = fabsf(x);
    float e = __expf(-2.0f * a);          // underflows to 0 for large a -> r=1
    float r = (1.0f - e) / (1.0f + e);
    return copysignf(r, x);
}

__global__ void __launch_bounds__(NTH, 1) lstm_persist(
    const float* __restrict__ x,
    const float* __restrict__ W_ih,
    const float* __restrict__ W_hh,
    const float* __restrict__ b_ih,
    const float* __restrict__ b_hh,
    const float* __restrict__ W1,
    const float* __restrict__ b1,
    const float* __restrict__ Wout,
    u64* __restrict__ hbuf,             // 2 x 256 packets, pre-zeroed
    float* __restrict__ out)
{
    const int w   = blockIdx.x;
    const int tid = threadIdx.x;
    const int wv  = tid >> 6;           // 0..7
    const int l   = tid & 63;
    const int rw  = l >> 3;             // 0..7
    const int j   = l & 7;              // K-chunk
    const int b   = rw & 3;             // elem within wave (0..3)
    const int gg  = rw >> 2;            // 0: gates i,f   1: gates g,o
    const bool is_out = (w == 0 && wv == 1);   // WG0 wave1 computes out[]

    __shared__ __align__(16) float h_lds[2][HID];   // parity double buffer
    __shared__ u64 gather_lds[16];                  // per-WG packet staging

    // wave owns elements {32w+4wv .. 32w+4wv+3}; this thread's elem:
    const int e_glob = 32 * w + 4 * wv + b;
    // two rows: gates 2*gg and 2*gg+1 of e_glob
    const int grow0 = (2 * gg + 0) * HID + e_glob;
    const int grow1 = (2 * gg + 1) * HID + e_glob;

    // ---- weights, j-rotated order to match the LDS read schedule ----
    float wr0[KW], wr1[KW], wi0[KX], wi1[KX];
#pragma unroll
    for (int kk = 0; kk < 16; ++kk) {
        const int p = (kk + 2 * j) & 15;
        const float4 v0 = *(const float4*)&W_hh[grow0 * HID + j * KW + 4 * p];
        wr0[4 * kk + 0] = v0.x; wr0[4 * kk + 1] = v0.y;
        wr0[4 * kk + 2] = v0.z; wr0[4 * kk + 3] = v0.w;
        const float4 v1 = *(const float4*)&W_hh[grow1 * HID + j * KW + 4 * p];
        wr1[4 * kk + 0] = v1.x; wr1[4 * kk + 1] = v1.y;
        wr1[4 * kk + 2] = v1.z; wr1[4 * kk + 3] = v1.w;
    }
#pragma unroll
    for (int k = 0; k < KX; k += 4) {
        const float4 v0 = *(const float4*)&W_ih[grow0 * INP + j * KX + k];
        wi0[k] = v0.x; wi0[k + 1] = v0.y; wi0[k + 2] = v0.z; wi0[k + 3] = v0.w;
        const float4 v1 = *(const float4*)&W_ih[grow1 * INP + j * KX + k];
        wi1[k] = v1.x; wi1[k + 1] = v1.y; wi1[k + 2] = v1.z; wi1[k + 3] = v1.w;
    }
    float brow0 = b_ih[grow0] + b_hh[grow0];
    float brow1 = b_ih[grow1] + b_hh[grow1];

    // out-projection weights (WG0 wave1): lane l covers h indices l + 64*i
    float weff_o[8];
    float be = 0.0f;
#pragma unroll
    for (int i = 0; i < 8; ++i) weff_o[i] = 0.0f;
    if (is_out) {
#pragma unroll
        for (int i = 0; i < 8; ++i) {
            float s = 0.0f;
            for (int p = 0; p < 25; ++p) s += Wout[p] * W1[p * HID + l + 64 * i];
            weff_o[i] = s;
        }
        for (int p = 0; p < 25; ++p) be += b1[p] * Wout[p];
    }
    // pin against in-loop memory clobbers
#pragma unroll
    for (int k = 0; k < KW; ++k) { asm volatile("" : "+v"(wr0[k]));
                                   asm volatile("" : "+v"(wr1[k])); }
#pragma unroll
    for (int k = 0; k < KX; ++k) { asm volatile("" : "+v"(wi0[k]));
                                   asm volatile("" : "+v"(wi1[k])); }
#pragma unroll
    for (int i = 0; i < 8; ++i) asm volatile("" : "+v"(weff_o[i]));
    asm volatile("" : "+v"(brow0));
    asm volatile("" : "+v"(brow1));
    asm volatile("" : "+v"(be));

    float c = 0.0f;
    float xa[KX];
#pragma unroll
    for (int k = 0; k < KX; ++k) xa[k] = x[j * KX + k];

    bool dead = false;   // safety latch: never hang the device

    for (u32 t = 0; t <= T_SEQ; ++t) {
        if (t == T_SEQ && w != 0) break;   // only WG0 runs the tail iteration

        // ---- x-dot partials for both rows (pure VALU; overlaps the poll) ---
        float p0a = 0.0f, p0b = 0.0f, p1a = 0.0f, p1b = 0.0f;
#pragma unroll
        for (int k = 0; k < KX; k += 2) {
            p0a += wi0[k + 0] * xa[k + 0];
            p0b += wi0[k + 1] * xa[k + 1];
            p1a += wi1[k + 0] * xa[k + 0];
            p1b += wi1[k + 1] * xa[k + 1];
        }
        // xa consumed -> prefetch x_{t+1}. Compute waves: before the barrier.
        const int tn = (t + 1 < T_SEQ) ? (int)(t + 1) : (T_SEQ - 1);
        if (wv != 0) {
#pragma unroll
            for (int k = 0; k < KX; k += 4) {
                const float4 x4 = *(const float4*)&x[tn * INP + j * KX + k];
                xa[k + 0] = x4.x; xa[k + 1] = x4.y;
                xa[k + 2] = x4.z; xa[k + 3] = x4.w;
            }
        }

        // ---- wave0 polls 256 packets (4 loads/lane, per-lane early-out) ----
        if (wv == 0 && !dead) {
            const u64* P = hbuf + (t & 1) * NPK;
            float2* HL = (float2*)h_lds[t & 1];
            bool mine = false;
            int guard = 0;
            while (true) {
                if (!mine) {
                    u64 pr[4];
                    bool ok = true;
#pragma unroll
                    for (int i = 0; i < 4; ++i) {
                        pr[i] = __hip_atomic_load(&P[l + 64 * i],
                                                  __ATOMIC_RELAXED,
                                                  __HIP_MEMORY_SCOPE_AGENT);
                        ok = ok && ((((u32)pr[i]) ^ t) & 15u) == 0u;
                    }
                    if (ok) {
#pragma unroll
                        for (int i = 0; i < 4; ++i) {
                            float2 hp;
                            hp.x = __uint_as_float((u32)pr[i]);
                            hp.y = __uint_as_float((u32)(pr[i] >> 32));
                            HL[l + 64 * i] = hp;   // h[2p], h[2p+1]
                        }
                        mine = true;
                    }
                }
                if (__ballot(mine) == ~0ull) break;
                if (++guard > (1 << 22)) { dead = true; break; }  // no hang
            }
        }
        __syncthreads();

        if (t < T_SEQ) {
            float a0 = p0a + p0b, a1 = p1a + p1b;
            float q0 = 0.0f, q1 = 0.0f;     // second chains
            const float4* hl4 = (const float4*)&h_lds[t & 1][j * KW];
#pragma unroll
            for (int kk = 0; kk < 16; ++kk) {
                const int p = (kk + 2 * j) & 15;
                const float4 h4 = hl4[p];
                a0 += wr0[4 * kk + 0] * h4.x + wr0[4 * kk + 1] * h4.y;
                q0 += wr0[4 * kk + 2] * h4.z + wr0[4 * kk + 3] * h4.w;
                a1 += wr1[4 * kk + 0] * h4.x + wr1[4 * kk + 1] * h4.y;
                q1 += wr1[4 * kk + 2] * h4.z + wr1[4 * kk + 3] * h4.w;
            }
            // poller's x-prefetch (after barrier, overlaps the h-dot)
            if (wv == 0) {
#pragma unroll
                for (int k = 0; k < KX; k += 4) {
                    const float4 x4 = *(const float4*)&x[tn * INP + j * KX + k];
                    xa[k + 0] = x4.x; xa[k + 1] = x4.y;
                    xa[k + 2] = x4.z; xa[k + 3] = x4.w;
                }
            }
            float acc0 = a0 + q0, acc1 = a1 + q1;
            // xor-butterfly over j for both rows
            acc0 += __shfl_xor(acc0, 1);
            acc1 += __shfl_xor(acc1, 1);
            acc0 += __shfl_xor(acc0, 2);
            acc1 += __shfl_xor(acc1, 2);
            acc0 += __shfl_xor(acc0, 4);
            acc1 += __shfl_xor(acc1, 4);
            acc0 += brow0;                  // gate 2*gg
            acc1 += brow1;                  // gate 2*gg + 1
            // activations on lanes rw<4 (gg=0): i=own acc0, f=own acc1,
            // g=acc0 of lane l+32 (gg=1), o=acc1 of lane l+32
            const float gG = __shfl(acc0, l + 32);
            const float oG = __shfl(acc1, l + 32);
            const float iv = fast_sigmoid(acc0);
            const float fv = fast_sigmoid(acc1);
            const float gv = fast_tanh(gG);
            const float ov = fast_sigmoid(oG);
            c = fv * c + iv * gv;
            const float hv = ov * fast_tanh(c);   // valid on lanes l<32
            // stage 2 packets/wave: elems at lanes 0,8,16,24 (j=0 of each rw)
            const float h0 = __shfl(hv, 0);
            const float h1 = __shfl(hv, 8);
            const float h2 = __shfl(hv, 16);
            const float h3 = __shfl(hv, 24);
            if (l == 0) {
                const u32 t0 = (__float_as_uint(h0) & ~15u) | ((t + 1) & 15u);
                const u32 t2 = (__float_as_uint(h2) & ~15u) | ((t + 1) & 15u);
                gather_lds[2 * wv + 0] =
                    ((u64)__float_as_uint(h1) << 32) | (u64)t0;
                gather_lds[2 * wv + 1] =
                    ((u64)__float_as_uint(h3) << 32) | (u64)t2;
            }
            __syncthreads();   // barrier B: all 16 packets staged
            // ---- coalesced publish: wave0 lanes 0-15, one 128B burst ----
            if (wv == 0 && l < 16) {
                __hip_atomic_store(&hbuf[((t + 1) & 1) * NPK + w * 16 + l],
                                   gather_lds[l],
                                   __ATOMIC_RELAXED, __HIP_MEMORY_SCOPE_AGENT);
            }
        }

        // out[t-1] = dot(h_{t-1}, w_eff) + b_eff — WG0 wave1, after publish
        if (is_out && t >= 1) {
            float pd = 0.0f;
#pragma unroll
            for (int i = 0; i < 8; ++i)
                pd += h_lds[t & 1][l + 64 * i] * weff_o[i];
            pd += __shfl_xor(pd, 1);
            pd += __shfl_xor(pd, 2);
            pd += __shfl_xor(pd, 4);
            pd += __shfl_xor(pd, 8);
            pd += __shfl_xor(pd, 16);
            pd += __shfl_xor(pd, 32);
            if (l == 0) out[t - 1] = pd + be;
        }
    }
}

extern "C" void kernel_launch(void* const* d_in, const int* in_sizes, int n_in,
                              void* d_out, int out_size, void* d_ws, size_t ws_size,
                              hipStream_t stream)
{
    const float* x    = (const float*)d_in[0];
    const float* W_ih = (const float*)d_in[1];
    const float* W_hh = (const float*)d_in[2];
    const float* b_ih = (const float*)d_in[3];
    const float* b_hh = (const float*)d_in[4];
    const float* W1   = (const float*)d_in[5];
    const float* b1   = (const float*)d_in[6];
    const float* Wout = (const float*)d_in[7];
    float* out = (float*)d_out;

    u64* hbuf = (u64*)d_ws;    // 2 x 256 packets = 4 KB

    // zero packets: tag nibble 0 + h 0 == valid initial state for step 0
    hipMemsetAsync(d_ws, 0, 2 * NPK * sizeof(u64), stream);
    lstm_persist<<<NWG, NTH, 0, stream>>>(x, W_ih, W_hh, b_ih, b_hh, W1, b1,
                                          Wout, hbuf, out);
}